// Round 2
// 428.412 us; speedup vs baseline: 1.0962x; 1.0962x over previous
//
#include <hip/hip_runtime.h>
#include <math.h>

#define TLEN 96000
#define NFFT 640
#define HOP  320
#define NF   321
#define NT   301
#define FT   (NF * NT)   // 96621

#define PI_F     3.14159265358979323846f
#define TWO_PI_F 6.28318530717958647692f

// cos/sin of pi/320 (window sample-to-sample angle delta)
#define CD640 0.99995180909f
#define SD640 0.00981731938f

// DFT-5 constants: cos/sin(2pi/5), cos/sin(4pi/5)
#define C5_1 0.30901699437494742f
#define S5_1 0.95105651629515357f
#define C5_2 (-0.80901699437494742f)
#define S5_2 0.58778525229247312f

// triu_indices(8), row-major
__constant__ int IU[36] = {0,0,0,0,0,0,0,0, 1,1,1,1,1,1,1, 2,2,2,2,2,2,
                           3,3,3,3,3, 4,4,4,4, 5,5,5, 6,6, 7};
__constant__ int JU[36] = {0,1,2,3,4,5,6,7, 1,2,3,4,5,6,7, 2,3,4,5,6,7,
                           3,4,5,6,7, 4,5,6,7, 5,6,7, 6,7, 7};

__device__ __forceinline__ float2 cmulf2(float2 a, float2 b) {
    float2 r; r.x = a.x * b.x - a.y * b.y; r.y = a.x * b.y + a.y * b.x; return r;
}

// ---------------------------------------------------------------------------
// 320-point complex DFT: radix-5 first stage (stride-64 input) + twiddle,
// then 6 self-sorting Stockham radix-2 stages on each of the 5 rows of 64.
// The LAST radix-2 stage (m=32, j=0, w=1) writes to de-scrambled positions,
// so the output is NATURAL order: Z[k] = B[k].
// All threads of the block must call (contains barriers). blockDim >= 160.
// ---------------------------------------------------------------------------
__device__ __forceinline__ void fft320(float2* A, float2* B, int tid) {
    if (tid < 64) {
        const int n2 = tid;
        const float2 x0 = A[n2];
        const float2 x1 = A[n2 + 64];
        const float2 x2 = A[n2 + 128];
        const float2 x3 = A[n2 + 192];
        const float2 x4 = A[n2 + 256];
        float2 t1; t1.x = x1.x + x4.x; t1.y = x1.y + x4.y;
        float2 t2; t2.x = x2.x + x3.x; t2.y = x2.y + x3.y;
        float2 t3; t3.x = x1.x - x4.x; t3.y = x1.y - x4.y;
        float2 t4; t4.x = x2.x - x3.x; t4.y = x2.y - x3.y;
        float2 u0; u0.x = x0.x + t1.x + t2.x; u0.y = x0.y + t1.y + t2.y;
        float2 u1, u2, u3, u4;
        u1.x = x0.x + C5_1 * t1.x + C5_2 * t2.x + S5_1 * t3.y + S5_2 * t4.y;
        u1.y = x0.y + C5_1 * t1.y + C5_2 * t2.y - S5_1 * t3.x - S5_2 * t4.x;
        u2.x = x0.x + C5_2 * t1.x + C5_1 * t2.x + S5_2 * t3.y - S5_1 * t4.y;
        u2.y = x0.y + C5_2 * t1.y + C5_1 * t2.y - S5_2 * t3.x + S5_1 * t4.x;
        u3.x = x0.x + C5_2 * t1.x + C5_1 * t2.x - S5_2 * t3.y + S5_1 * t4.y;
        u3.y = x0.y + C5_2 * t1.y + C5_1 * t2.y + S5_2 * t3.x - S5_1 * t4.x;
        u4.x = x0.x + C5_1 * t1.x + C5_2 * t2.x - S5_1 * t3.y - S5_2 * t4.y;
        u4.y = x0.y + C5_1 * t1.y + C5_2 * t2.y + S5_1 * t3.x + S5_2 * t4.x;
        float sn, cs;
        __sincosf((TWO_PI_F / 320.0f) * (float)n2, &sn, &cs);
        float2 w1; w1.x = cs; w1.y = -sn;          // e^{-i 2pi n2/320}
        const float2 w2 = cmulf2(w1, w1);
        const float2 w3 = cmulf2(w2, w1);
        const float2 w4 = cmulf2(w2, w2);
        B[n2]       = u0;
        B[64 + n2]  = cmulf2(u1, w1);
        B[128 + n2] = cmulf2(u2, w2);
        B[192 + n2] = cmulf2(u3, w3);
        B[256 + n2] = cmulf2(u4, w4);
    }
    __syncthreads();
    float2* src = B;
    float2* dst = A;
#pragma unroll
    for (int s = 0; s < 5; ++s) {
        if (tid < 160) {
            const int r  = tid >> 5;
            const int b  = tid & 31;
            const int m  = 1 << s;
            const int kk = b & (m - 1);
            const int jm = b - kk;                 // j*m
            const int j  = b >> s;
            const int base = r << 6;
            const float2 c0 = src[base + b];
            const float2 c1 = src[base + b + 32];
            float2 sm; sm.x = c0.x + c1.x; sm.y = c0.y + c1.y;
            float2 df; df.x = c0.x - c1.x; df.y = c0.y - c1.y;
            float sn, cs;
            __sincosf(PI_F * (float)j / (float)(32 >> s), &sn, &cs);
            float2 w; w.x = cs; w.y = -sn;         // e^{-i pi j / l}
            dst[base + kk + 2 * jm]     = sm;
            dst[base + kk + 2 * jm + m] = cmulf2(df, w);
        }
        __syncthreads();
        float2* t = src; src = dst; dst = t;
    }
    // 5 loop stages: B->A->B->A->B, so src==A here.  Final stage (m=32, j=0,
    // w=1): row r, position j holds Z[5j+r]; write straight to natural order.
    if (tid < 160) {
        const int r = tid >> 5;
        const int b = tid & 31;
        const int base = r << 6;
        const float2 c0 = src[base + b];
        const float2 c1 = src[base + b + 32];
        float2 sm; sm.x = c0.x + c1.x; sm.y = c0.y + c1.y;
        float2 df; df.x = c0.x - c1.x; df.y = c0.y - c1.y;
        dst[5 * b + r]       = sm;   // Z[5*b + r]
        dst[5 * b + 160 + r] = df;   // Z[5*(b+32) + r]
    }
    __syncthreads();
    // result: B[k] = Z[k], natural order
}

// ---------------------------------------------------------------------------
// K1: STFT of 17 signals (16 = x[b][c], 1 = ref_g batch 0) via real FFT-640:
// z[n] = wa[2n] + i*wa[2n+1] -> complex FFT-320 -> rFFT unpack.
// ---------------------------------------------------------------------------
__global__ __launch_bounds__(192) void k_stft(const float* __restrict__ x,
                                              const float* __restrict__ ref_g,
                                              float2* __restrict__ Sx,
                                              float2* __restrict__ refS) {
    const int f   = blockIdx.x;   // 0..300 (frame)
    const int s   = blockIdx.y;   // 0..16  (signal)
    const int tid = threadIdx.x;  // 0..191

    __shared__ __align__(16) float2 A[320];
    __shared__ __align__(16) float2 B[320];

    const float* sig = (s < 16) ? (x + (size_t)s * TLEN) : ref_g;

    if (tid < 160) {
#pragma unroll
        for (int h = 0; h < 2; ++h) {
            const int n = tid + 160 * h;            // 0..319
            const int p = f * HOP - HOP + 2 * n;    // sample index of wa[2n]
            const float v0 = (p >= 0 && p < TLEN) ? sig[p] : 0.0f;
            const float v1 = (p >= -1 && p + 1 < TLEN) ? sig[p + 1] : 0.0f;
            float sn, cs;
            __sincosf((PI_F / 160.0f) * (float)n, &sn, &cs);  // angle of win[2n]
            const float w0  = 0.5f - 0.5f * cs;
            const float cs1 = cs * CD640 - sn * SD640;        // cos(theta + pi/320)
            const float w1  = 0.5f - 0.5f * cs1;
            float2 z; z.x = v0 * w0; z.y = v1 * w1;
            A[n] = z;
        }
    }
    __syncthreads();

    fft320(A, B, tid);

    if (tid <= 160) {
        const int k  = tid;                 // handle pair (k, 320-k)
        const int kp = 320 - k;
        const int km = (k == 0) ? 0 : kp;   // (320-k) mod 320  (320 is NOT pow2!)
        const float2 Zk = B[k];
        float2 Zc = B[km]; Zc.y = -Zc.y;    // conj(Z[(320-k) mod 320])
        const float Er = 0.5f * (Zk.x + Zc.x);
        const float Ei = 0.5f * (Zk.y + Zc.y);
        const float Dr = 0.5f * (Zk.x - Zc.x);
        const float Di = 0.5f * (Zk.y - Zc.y);
        const float Gr = Di, Gi = -Dr;      // G = O = -i*D
        float sp, cp;
        __sincosf((PI_F / 320.0f) * (float)k, &sp, &cp);  // phi = 2pi k/640
        float2 Xk;                          // X_k = E + e^{-i phi} O
        Xk.x = Er + cp * Gr + sp * Gi;
        Xk.y = Ei + cp * Gi - sp * Gr;
        float2 Xp;                          // X_{320-k} = conj(E) - e^{+i phi} conj(O)
        Xp.x =  Er - (cp * Di - sp * Dr);
        Xp.y = -Ei - (cp * Dr + sp * Di);
        float2* base = (s < 16) ? (Sx + (size_t)s * FT) : refS;
        base[(size_t)k  * NT + f] = Xk;
        base[(size_t)kp * NT + f] = Xp;     // k=0 writes Nyquist bin 320
    }
}

// ---------------------------------------------------------------------------
// K2: covariance features.  feats[b][74][F][T].  (unchanged)
// ---------------------------------------------------------------------------
__global__ void k_cov(const float2* __restrict__ Sx, float* __restrict__ feats) {
    int idx = blockIdx.x * blockDim.x + threadIdx.x;
    if (idx >= 2 * 37 * FT) return;
    const int kt  = idx % FT;
    const int job = (idx / FT) % 37;
    const int b   = idx / (37 * FT);
    const float2* Sb = Sx + (size_t)b * 8 * FT;
    float* fb = feats + (size_t)b * 74 * FT;
    if (job == 36) {
        const float2 r = Sb[(size_t)3 * FT + kt];   // REF_CH = 3
        fb[(size_t)72 * FT + kt] = r.x;
        fb[(size_t)73 * FT + kt] = r.y;
    } else {
        const float2 a = Sb[(size_t)IU[job] * FT + kt];
        const float2 c = Sb[(size_t)JU[job] * FT + kt];
        fb[(size_t)(2 * job)     * FT + kt] = a.x * c.x + a.y * c.y;
        fb[(size_t)(2 * job + 1) * FT + kt] = a.y * c.x - a.x * c.y;
    }
}

// ---------------------------------------------------------------------------
// K3: deep filtering, batch 0 only.  (unchanged)
// ---------------------------------------------------------------------------
__global__ void k_dfilter(const float2* __restrict__ rtf,
                          const float2* __restrict__ refS,
                          float2* __restrict__ est) {
    int idx = blockIdx.x * blockDim.x + threadIdx.x;
    if (idx >= 7 * FT) return;
    const int t = idx % NT;
    const int f = (idx / NT) % NF;
    const int m = idx / FT;
    float er = 0.0f, ei = 0.0f;
#pragma unroll
    for (int ki = 0; ki < 3; ++ki) {
        const int ff = f + ki - 1;
#pragma unroll
        for (int kj = 0; kj < 9; ++kj) {
            const int tt = t + kj - 4;
            float pr = 0.0f, pi = 0.0f;
            if ((unsigned)ff < (unsigned)NF && (unsigned)tt < (unsigned)NT) {
                const float2 p = refS[(size_t)ff * NT + tt];
                pr = p.x; pi = p.y;
            }
            const float2 r = rtf[(size_t)(((m * 3 + ki) * 9 + kj) * NF + f) * NT + t];
            er = fmaf(r.x, pr, er); er = fmaf(-r.y, pi, er);
            ei = fmaf(r.x, pi, ei); ei = fmaf( r.y, pr, ei);
        }
    }
    float2 o; o.x = er; o.y = ei;
    est[idx] = o;   // layout [m][f][t]
}

// ---------------------------------------------------------------------------
// K4: per-frame irfft(640)*win via real-iFFT packing + complex FFT-320.
// Z_k = E_k + i O_k built from X; forward FFT of conj(Z); z[n] = conj(F[n])/320.
// a[2n] = F[n].x/320, a[2n+1] = -F[n].y/320.  Writes windowed frame (float2).
// ---------------------------------------------------------------------------
__global__ __launch_bounds__(320) void k_iframes(const float2* __restrict__ est,
                                                 float* __restrict__ frames) {
    const int f   = blockIdx.x;  // frame
    const int m   = blockIdx.y;  // est channel
    const int tid = threadIdx.x; // 0..319

    __shared__ __align__(16) float2 Xs[322];
    __shared__ __align__(16) float2 A[320];
    __shared__ __align__(16) float2 B[320];

    {
        const float2* eb = est + (size_t)m * NF * NT + f;
        Xs[tid] = eb[(size_t)tid * NT];
        if (tid == 0) Xs[320] = eb[(size_t)320 * NT];
    }
    __syncthreads();

    if (tid <= 160) {
        const int k = tid;
        const float2 Xk = Xs[k];
        const float2 X2 = Xs[320 - k];
        const float Er = 0.5f * (Xk.x + X2.x);
        const float Ei = 0.5f * (Xk.y - X2.y);
        const float Hr = 0.5f * (Xk.x - X2.x);
        const float Hi = 0.5f * (Xk.y + X2.y);
        float sp, cp;
        __sincosf((PI_F / 320.0f) * (float)k, &sp, &cp);  // phi = 2pi k/640
        const float Or = cp * Hr - sp * Hi;               // O = e^{+i phi} H
        const float Oi = cp * Hi + sp * Hr;
        float2 vk;                   // conj(Z_k), Z_k = (Er - Oi) + i(Ei + Or)
        vk.x = Er - Oi; vk.y = -(Ei + Or);
        A[k] = vk;
        if (k >= 1 && k <= 159) {    // conj(Z_{320-k}), Z_{320-k} = (Er+Oi) + i(Or-Ei)
            float2 vp; vp.x = Er + Oi; vp.y = Ei - Or;
            A[320 - k] = vp;
        }
    }
    __syncthreads();

    fft320(A, B, tid);

    {
        const int n = tid;                       // output sample pair (2n, 2n+1)
        const float2 w = B[n];                   // F[n], natural order
        float sn, cs;
        __sincosf((PI_F / 160.0f) * (float)n, &sn, &cs);  // angle of win[2n]
        const float w0  = 0.5f - 0.5f * cs;
        const float cs1 = cs * CD640 - sn * SD640;
        const float w1  = 0.5f - 0.5f * cs1;
        const float inv = 1.0f / 320.0f;
        float2 o; o.x = w.x * inv * w0; o.y = -w.y * inv * w1;
        float* fb = frames + ((size_t)m * NT + f) * NFFT;
        *(float2*)(fb + 2 * n) = o;
    }
}

// ---------------------------------------------------------------------------
// K5: overlap-add + wsum normalization + interleaved [t][c] output. (unchanged)
// ---------------------------------------------------------------------------
__global__ void k_ola(const float* __restrict__ frames,
                      const float* __restrict__ ref_g,
                      float* __restrict__ out0) {
    int idx = blockIdx.x * blockDim.x + threadIdx.x;
    if (idx >= 8 * TLEN) return;
    const int c = idx & 7;
    const int t = idx >> 3;
    float o;
    if (c == 3) {
        o = ref_g[t];
    } else {
        const int m  = (c < 3) ? c : (c - 1);
        const int f1 = t / HOP + 1;          // in [1,300]
        const int n1 = t % HOP;
        const float a = frames[((size_t)m * NT + f1)     * NFFT + n1];
        const float b = frames[((size_t)m * NT + f1 - 1) * NFFT + n1 + 320];
        const float cw = cosf((TWO_PI_F / NFFT) * (float)n1);
        const float w0 = 0.5f - 0.5f * cw;
        const float w1 = 0.5f + 0.5f * cw;
        float ws = w0 * w0 + w1 * w1;
        ws = (ws > 1e-11f) ? ws : 1.0f;
        o = (a + b) / ws;
    }
    out0[idx] = o;
}

extern "C" void kernel_launch(void* const* d_in, const int* in_sizes, int n_in,
                              void* d_out, int out_size, void* d_ws, size_t ws_size,
                              hipStream_t stream) {
    const float* x     = (const float*)d_in[0];   // [2,8,96000]
    const float* rtf   = (const float*)d_in[1];   // [2,7,3,9,321,301,2]
    const float* ref_g = (const float*)d_in[2];   // [2,1,96000]

    float* out0  = (float*)d_out;                 // [96000,8]
    float* feats = (float*)d_out + (size_t)8 * TLEN;  // [2,74,321,301]

    // workspace carve-up (~24 MB total)
    float2* Sx     = (float2*)d_ws;                       // 16*FT float2
    float2* refS   = Sx + (size_t)16 * FT;                // FT float2
    float2* est    = refS + (size_t)FT;                   // 7*FT float2
    float*  frames = (float*)(est + (size_t)7 * FT);      // 7*301*640 floats

    k_stft<<<dim3(NT, 17), 192, 0, stream>>>(x, ref_g, Sx, refS);
    {
        const int total = 2 * 37 * FT;
        k_cov<<<(total + 255) / 256, 256, 0, stream>>>(Sx, feats);
    }
    {
        const int total = 7 * FT;
        k_dfilter<<<(total + 255) / 256, 256, 0, stream>>>(
            (const float2*)rtf, refS, est);
    }
    k_iframes<<<dim3(NT, 7), 320, 0, stream>>>(est, frames);
    {
        const int total = 8 * TLEN;
        k_ola<<<(total + 255) / 256, 256, 0, stream>>>(frames, ref_g, out0);
    }
}

// Round 3
// 419.035 us; speedup vs baseline: 1.1207x; 1.0224x over previous
//
#include <hip/hip_runtime.h>
#include <math.h>

#define TLEN 96000
#define NFFT 640
#define HOP  320
#define NF   321
#define NT   301
#define FT   (NF * NT)   // 96621

#define PI_F     3.14159265358979323846f
#define TWO_PI_F 6.28318530717958647692f

// cos/sin of pi/320 (window sample-to-sample angle delta)
#define CD640 0.99995180909f
#define SD640 0.00981731938f

// DFT-5 constants: cos/sin(2pi/5), cos/sin(4pi/5)
#define C5_1 0.30901699437494742f
#define S5_1 0.95105651629515357f
#define C5_2 (-0.80901699437494742f)
#define S5_2 0.58778525229247312f

typedef float vf2 __attribute__((ext_vector_type(2)));

// triu_indices(8), row-major
__constant__ int IU[36] = {0,0,0,0,0,0,0,0, 1,1,1,1,1,1,1, 2,2,2,2,2,2,
                           3,3,3,3,3, 4,4,4,4, 5,5,5, 6,6, 7};
__constant__ int JU[36] = {0,1,2,3,4,5,6,7, 1,2,3,4,5,6,7, 2,3,4,5,6,7,
                           3,4,5,6,7, 4,5,6,7, 5,6,7, 6,7, 7};

__device__ __forceinline__ float2 cmulf2(float2 a, float2 b) {
    float2 r; r.x = a.x * b.x - a.y * b.y; r.y = a.x * b.y + a.y * b.x; return r;
}

// ---------------------------------------------------------------------------
// 320-point complex DFT: radix-5 first stage (stride-64 input) + twiddle,
// then 6 self-sorting Stockham radix-2 stages on each of the 5 rows of 64.
// The LAST radix-2 stage (m=32, j=0, w=1) writes to de-scrambled positions,
// so the output is NATURAL order: Z[k] = B[k].
// All threads of the block must call (contains block-wide barriers).
// l is the LOCAL thread id within this FFT's 160-thread group.
// ---------------------------------------------------------------------------
__device__ __forceinline__ void fft320(float2* A, float2* B, int l) {
    if (l < 64) {
        const int n2 = l;
        const float2 x0 = A[n2];
        const float2 x1 = A[n2 + 64];
        const float2 x2 = A[n2 + 128];
        const float2 x3 = A[n2 + 192];
        const float2 x4 = A[n2 + 256];
        float2 t1; t1.x = x1.x + x4.x; t1.y = x1.y + x4.y;
        float2 t2; t2.x = x2.x + x3.x; t2.y = x2.y + x3.y;
        float2 t3; t3.x = x1.x - x4.x; t3.y = x1.y - x4.y;
        float2 t4; t4.x = x2.x - x3.x; t4.y = x2.y - x3.y;
        float2 u0; u0.x = x0.x + t1.x + t2.x; u0.y = x0.y + t1.y + t2.y;
        float2 u1, u2, u3, u4;
        u1.x = x0.x + C5_1 * t1.x + C5_2 * t2.x + S5_1 * t3.y + S5_2 * t4.y;
        u1.y = x0.y + C5_1 * t1.y + C5_2 * t2.y - S5_1 * t3.x - S5_2 * t4.x;
        u2.x = x0.x + C5_2 * t1.x + C5_1 * t2.x + S5_2 * t3.y - S5_1 * t4.y;
        u2.y = x0.y + C5_2 * t1.y + C5_1 * t2.y - S5_2 * t3.x + S5_1 * t4.x;
        u3.x = x0.x + C5_2 * t1.x + C5_1 * t2.x - S5_2 * t3.y + S5_1 * t4.y;
        u3.y = x0.y + C5_2 * t1.y + C5_1 * t2.y + S5_2 * t3.x - S5_1 * t4.x;
        u4.x = x0.x + C5_1 * t1.x + C5_2 * t2.x - S5_1 * t3.y - S5_2 * t4.y;
        u4.y = x0.y + C5_1 * t1.y + C5_2 * t2.y + S5_1 * t3.x + S5_2 * t4.x;
        float sn, cs;
        __sincosf((TWO_PI_F / 320.0f) * (float)n2, &sn, &cs);
        float2 w1; w1.x = cs; w1.y = -sn;          // e^{-i 2pi n2/320}
        const float2 w2 = cmulf2(w1, w1);
        const float2 w3 = cmulf2(w2, w1);
        const float2 w4 = cmulf2(w2, w2);
        B[n2]       = u0;
        B[64 + n2]  = cmulf2(u1, w1);
        B[128 + n2] = cmulf2(u2, w2);
        B[192 + n2] = cmulf2(u3, w3);
        B[256 + n2] = cmulf2(u4, w4);
    }
    __syncthreads();
    float2* src = B;
    float2* dst = A;
#pragma unroll
    for (int s = 0; s < 5; ++s) {
        if (l < 160) {
            const int r  = l >> 5;
            const int b  = l & 31;
            const int m  = 1 << s;
            const int kk = b & (m - 1);
            const int jm = b - kk;                 // j*m
            const int j  = b >> s;
            const int base = r << 6;
            const float2 c0 = src[base + b];
            const float2 c1 = src[base + b + 32];
            float2 sm; sm.x = c0.x + c1.x; sm.y = c0.y + c1.y;
            float2 df; df.x = c0.x - c1.x; df.y = c0.y - c1.y;
            float sn, cs;
            __sincosf(PI_F * (float)j / (float)(32 >> s), &sn, &cs);
            float2 w; w.x = cs; w.y = -sn;         // e^{-i pi j / l}
            dst[base + kk + 2 * jm]     = sm;
            dst[base + kk + 2 * jm + m] = cmulf2(df, w);
        }
        __syncthreads();
        float2* t = src; src = dst; dst = t;
    }
    // 5 loop stages: B->A->B->A->B, so src==A here.  Final stage (m=32, j=0,
    // w=1): row r, position j holds Z[5j+r]; write straight to natural order.
    if (l < 160) {
        const int r = l >> 5;
        const int b = l & 31;
        const int base = r << 6;
        const float2 c0 = src[base + b];
        const float2 c1 = src[base + b + 32];
        float2 sm; sm.x = c0.x + c1.x; sm.y = c0.y + c1.y;
        float2 df; df.x = c0.x - c1.x; df.y = c0.y - c1.y;
        dst[5 * b + r]       = sm;   // Z[5*b + r]
        dst[5 * b + 160 + r] = df;   // Z[5*(b+32) + r]
    }
    __syncthreads();
    // result: B[k] = Z[k], natural order
}

// ---------------------------------------------------------------------------
// K1: STFT of 17 signals (16 = x[b][c], 1 = ref_g batch 0) via real FFT-640.
// TWO frames per block: group g = tid/160 handles frame f = 2*bx + g with
// local thread id l = tid % 160.  z[n] = wa[2n] + i*wa[2n+1] -> FFT-320 ->
// rFFT unpack (thread l=0 also handles the self-conjugate bin k=160).
// ---------------------------------------------------------------------------
__global__ __launch_bounds__(320) void k_stft(const float* __restrict__ x,
                                              const float* __restrict__ ref_g,
                                              float2* __restrict__ Sx,
                                              float2* __restrict__ refS) {
    const int s   = blockIdx.y;        // 0..16 (signal)
    const int tid = threadIdx.x;       // 0..319
    const int g   = tid / 160;         // FFT group within block
    const int l   = tid - g * 160;     // local thread id
    const int f   = 2 * blockIdx.x + g;        // frame 0..301 (301 invalid)
    const bool valid = (f < NT);

    __shared__ __align__(16) float2 A[2][320];
    __shared__ __align__(16) float2 B[2][320];
    float2* Ag = A[g];
    float2* Bg = B[g];

    const float* sig = (s < 16) ? (x + (size_t)s * TLEN) : ref_g;

#pragma unroll
    for (int h = 0; h < 2; ++h) {
        const int n = l + 160 * h;              // 0..319
        float v0 = 0.0f, v1 = 0.0f;
        if (valid) {
            const int p = f * HOP - HOP + 2 * n;    // sample index of wa[2n]
            v0 = (p >= 0 && p < TLEN) ? sig[p] : 0.0f;
            v1 = (p >= -1 && p + 1 < TLEN) ? sig[p + 1] : 0.0f;
        }
        float sn, cs;
        __sincosf((PI_F / 160.0f) * (float)n, &sn, &cs);  // angle of win[2n]
        const float w0  = 0.5f - 0.5f * cs;
        const float cs1 = cs * CD640 - sn * SD640;        // cos(theta + pi/320)
        const float w1  = 0.5f - 0.5f * cs1;
        float2 z; z.x = v0 * w0; z.y = v1 * w1;
        Ag[n] = z;
    }
    __syncthreads();

    fft320(Ag, Bg, l);

    if (valid) {
        float2* base = (s < 16) ? (Sx + (size_t)s * FT) : refS;
        for (int k = l; k <= 160; k += 160) {   // l=0 also does k=160
            const int kp = 320 - k;
            const int km = (k == 0) ? 0 : kp;   // (320-k) mod 320
            const float2 Zk = Bg[k];
            float2 Zc = Bg[km]; Zc.y = -Zc.y;   // conj(Z[(320-k) mod 320])
            const float Er = 0.5f * (Zk.x + Zc.x);
            const float Ei = 0.5f * (Zk.y + Zc.y);
            const float Dr = 0.5f * (Zk.x - Zc.x);
            const float Di = 0.5f * (Zk.y - Zc.y);
            const float Gr = Di, Gi = -Dr;      // O = -i*D
            float sp, cp;
            __sincosf((PI_F / 320.0f) * (float)k, &sp, &cp);  // phi = 2pi k/640
            float2 Xk;                          // X_k = E + e^{-i phi} O
            Xk.x = Er + cp * Gr + sp * Gi;
            Xk.y = Ei + cp * Gi - sp * Gr;
            float2 Xp;                          // X_{320-k} = conj(E) - e^{+i phi} conj(O)
            Xp.x =  Er - (cp * Di - sp * Dr);
            Xp.y = -Ei - (cp * Dr + sp * Di);
            base[(size_t)k  * NT + f] = Xk;
            base[(size_t)kp * NT + f] = Xp;     // k=0 writes Nyquist bin 320
        }
    }
}

// ---------------------------------------------------------------------------
// K2: covariance features.  feats[b][74][F][T].
// Non-temporal stores: feats is a write-once output; keep Sx/refS in L2.
// ---------------------------------------------------------------------------
__global__ void k_cov(const float2* __restrict__ Sx, float* __restrict__ feats) {
    int idx = blockIdx.x * blockDim.x + threadIdx.x;
    if (idx >= 2 * 37 * FT) return;
    const int kt  = idx % FT;
    const int job = (idx / FT) % 37;
    const int b   = idx / (37 * FT);
    const float2* Sb = Sx + (size_t)b * 8 * FT;
    float* fb = feats + (size_t)b * 74 * FT;
    if (job == 36) {
        const float2 r = Sb[(size_t)3 * FT + kt];   // REF_CH = 3
        __builtin_nontemporal_store(r.x, &fb[(size_t)72 * FT + kt]);
        __builtin_nontemporal_store(r.y, &fb[(size_t)73 * FT + kt]);
    } else {
        const float2 a = Sb[(size_t)IU[job] * FT + kt];
        const float2 c = Sb[(size_t)JU[job] * FT + kt];
        __builtin_nontemporal_store(a.x * c.x + a.y * c.y,
                                    &fb[(size_t)(2 * job)     * FT + kt]);
        __builtin_nontemporal_store(a.y * c.x - a.x * c.y,
                                    &fb[(size_t)(2 * job + 1) * FT + kt]);
    }
}

// ---------------------------------------------------------------------------
// K3: deep filtering, batch 0 only.  rtf (146 MB, read exactly once) is
// loaded non-temporally so it doesn't evict refS/est from L2.
// ---------------------------------------------------------------------------
__global__ void k_dfilter(const float2* __restrict__ rtf,
                          const float2* __restrict__ refS,
                          float2* __restrict__ est) {
    int idx = blockIdx.x * blockDim.x + threadIdx.x;
    if (idx >= 7 * FT) return;
    const int t = idx % NT;
    const int f = (idx / NT) % NF;
    const int m = idx / FT;
    float er = 0.0f, ei = 0.0f;
#pragma unroll
    for (int ki = 0; ki < 3; ++ki) {
        const int ff = f + ki - 1;
#pragma unroll
        for (int kj = 0; kj < 9; ++kj) {
            const int tt = t + kj - 4;
            float pr = 0.0f, pi = 0.0f;
            if ((unsigned)ff < (unsigned)NF && (unsigned)tt < (unsigned)NT) {
                const float2 p = refS[(size_t)ff * NT + tt];
                pr = p.x; pi = p.y;
            }
            const vf2 r = __builtin_nontemporal_load(
                (const vf2*)&rtf[(size_t)(((m * 3 + ki) * 9 + kj) * NF + f) * NT + t]);
            er = fmaf(r.x, pr, er); er = fmaf(-r.y, pi, er);
            ei = fmaf(r.x, pi, ei); ei = fmaf( r.y, pr, ei);
        }
    }
    float2 o; o.x = er; o.y = ei;
    est[idx] = o;   // layout [m][f][t]
}

// ---------------------------------------------------------------------------
// K4: per-frame irfft(640)*win via real-iFFT packing + complex FFT-320.
// Z_k = E_k + i O_k built from X; forward FFT of conj(Z); z[n] = conj(F[n])/320.
// a[2n] = F[n].x/320, a[2n+1] = -F[n].y/320.  Writes windowed frame (float2).
// ---------------------------------------------------------------------------
__global__ __launch_bounds__(320) void k_iframes(const float2* __restrict__ est,
                                                 float* __restrict__ frames) {
    const int f   = blockIdx.x;  // frame
    const int m   = blockIdx.y;  // est channel
    const int tid = threadIdx.x; // 0..319

    __shared__ __align__(16) float2 Xs[322];
    __shared__ __align__(16) float2 A[320];
    __shared__ __align__(16) float2 B[320];

    {
        const float2* eb = est + (size_t)m * NF * NT + f;
        Xs[tid] = eb[(size_t)tid * NT];
        if (tid == 0) Xs[320] = eb[(size_t)320 * NT];
    }
    __syncthreads();

    if (tid <= 160) {
        const int k = tid;
        const float2 Xk = Xs[k];
        const float2 X2 = Xs[320 - k];
        const float Er = 0.5f * (Xk.x + X2.x);
        const float Ei = 0.5f * (Xk.y - X2.y);
        const float Hr = 0.5f * (Xk.x - X2.x);
        const float Hi = 0.5f * (Xk.y + X2.y);
        float sp, cp;
        __sincosf((PI_F / 320.0f) * (float)k, &sp, &cp);  // phi = 2pi k/640
        const float Or = cp * Hr - sp * Hi;               // O = e^{+i phi} H
        const float Oi = cp * Hi + sp * Hr;
        float2 vk;                   // conj(Z_k), Z_k = (Er - Oi) + i(Ei + Or)
        vk.x = Er - Oi; vk.y = -(Ei + Or);
        A[k] = vk;
        if (k >= 1 && k <= 159) {    // conj(Z_{320-k}), Z_{320-k} = (Er+Oi) + i(Or-Ei)
            float2 vp; vp.x = Er + Oi; vp.y = Ei - Or;
            A[320 - k] = vp;
        }
    }
    __syncthreads();

    fft320(A, B, tid);

    {
        const int n = tid;                       // output sample pair (2n, 2n+1)
        const float2 w = B[n];                   // F[n], natural order
        float sn, cs;
        __sincosf((PI_F / 160.0f) * (float)n, &sn, &cs);  // angle of win[2n]
        const float w0  = 0.5f - 0.5f * cs;
        const float cs1 = cs * CD640 - sn * SD640;
        const float w1  = 0.5f - 0.5f * cs1;
        const float inv = 1.0f / 320.0f;
        float2 o; o.x = w.x * inv * w0; o.y = -w.y * inv * w1;
        float* fb = frames + ((size_t)m * NT + f) * NFFT;
        *(float2*)(fb + 2 * n) = o;
    }
}

// ---------------------------------------------------------------------------
// K5: overlap-add + wsum normalization + interleaved [t][c] output write.
// out0 is write-once: non-temporal stores.
// ---------------------------------------------------------------------------
__global__ void k_ola(const float* __restrict__ frames,
                      const float* __restrict__ ref_g,
                      float* __restrict__ out0) {
    int idx = blockIdx.x * blockDim.x + threadIdx.x;
    if (idx >= 8 * TLEN) return;
    const int c = idx & 7;
    const int t = idx >> 3;
    float o;
    if (c == 3) {
        o = ref_g[t];
    } else {
        const int m  = (c < 3) ? c : (c - 1);
        const int f1 = t / HOP + 1;          // in [1,300]
        const int n1 = t % HOP;
        const float a = frames[((size_t)m * NT + f1)     * NFFT + n1];
        const float b = frames[((size_t)m * NT + f1 - 1) * NFFT + n1 + 320];
        const float cw = cosf((TWO_PI_F / NFFT) * (float)n1);
        const float w0 = 0.5f - 0.5f * cw;
        const float w1 = 0.5f + 0.5f * cw;
        float ws = w0 * w0 + w1 * w1;
        ws = (ws > 1e-11f) ? ws : 1.0f;
        o = (a + b) / ws;
    }
    __builtin_nontemporal_store(o, &out0[idx]);
}

extern "C" void kernel_launch(void* const* d_in, const int* in_sizes, int n_in,
                              void* d_out, int out_size, void* d_ws, size_t ws_size,
                              hipStream_t stream) {
    const float* x     = (const float*)d_in[0];   // [2,8,96000]
    const float* rtf   = (const float*)d_in[1];   // [2,7,3,9,321,301,2]
    const float* ref_g = (const float*)d_in[2];   // [2,1,96000]

    float* out0  = (float*)d_out;                 // [96000,8]
    float* feats = (float*)d_out + (size_t)8 * TLEN;  // [2,74,321,301]

    // workspace carve-up (~24 MB total)
    float2* Sx     = (float2*)d_ws;                       // 16*FT float2
    float2* refS   = Sx + (size_t)16 * FT;                // FT float2
    float2* est    = refS + (size_t)FT;                   // 7*FT float2
    float*  frames = (float*)(est + (size_t)7 * FT);      // 7*301*640 floats

    k_stft<<<dim3((NT + 1) / 2, 17), 320, 0, stream>>>(x, ref_g, Sx, refS);
    {
        const int total = 2 * 37 * FT;
        k_cov<<<(total + 255) / 256, 256, 0, stream>>>(Sx, feats);
    }
    {
        const int total = 7 * FT;
        k_dfilter<<<(total + 255) / 256, 256, 0, stream>>>(
            (const float2*)rtf, refS, est);
    }
    k_iframes<<<dim3(NT, 7), 320, 0, stream>>>(est, frames);
    {
        const int total = 8 * TLEN;
        k_ola<<<(total + 255) / 256, 256, 0, stream>>>(frames, ref_g, out0);
    }
}

// Round 4
// 412.705 us; speedup vs baseline: 1.1379x; 1.0153x over previous
//
#include <hip/hip_runtime.h>
#include <math.h>

#define TLEN 96000
#define NFFT 640
#define HOP  320
#define NF   321
#define NT   301
#define FT   (NF * NT)   // 96621

#define PI_F     3.14159265358979323846f
#define TWO_PI_F 6.28318530717958647692f

// cos/sin of pi/320 (window sample-to-sample angle delta)
#define CD640 0.99995180909f
#define SD640 0.00981731938f

// DFT-5 constants: cos/sin(2pi/5), cos/sin(4pi/5)
#define C5_1 0.30901699437494742f
#define S5_1 0.95105651629515357f
#define C5_2 (-0.80901699437494742f)
#define S5_2 0.58778525229247312f

// fused cov+dfilter grid split
#define COV_TOTAL (2 * FT)                       // 193242
#define COV_BLOCKS ((COV_TOTAL + 255) / 256)     // 755
#define DF_TOTAL (7 * FT)                        // 676347
#define DF_BLOCKS ((DF_TOTAL + 255) / 256)       // 2643

typedef float vf2 __attribute__((ext_vector_type(2)));

__device__ __forceinline__ float2 cmulf2(float2 a, float2 b) {
    float2 r; r.x = a.x * b.x - a.y * b.y; r.y = a.x * b.y + a.y * b.x; return r;
}

// ---------------------------------------------------------------------------
// 320-point complex DFT: radix-5 first stage (stride-64 input) + twiddle,
// then 6 self-sorting Stockham radix-2 stages on each of the 5 rows of 64.
// The LAST radix-2 stage (m=32, j=0, w=1) writes to de-scrambled positions,
// so the output is NATURAL order: Z[k] = B[k].
// All threads of the block must call (contains block-wide barriers).
// l is the LOCAL thread id within this FFT's 160-thread group.
// ---------------------------------------------------------------------------
__device__ __forceinline__ void fft320(float2* A, float2* B, int l) {
    if (l < 64) {
        const int n2 = l;
        const float2 x0 = A[n2];
        const float2 x1 = A[n2 + 64];
        const float2 x2 = A[n2 + 128];
        const float2 x3 = A[n2 + 192];
        const float2 x4 = A[n2 + 256];
        float2 t1; t1.x = x1.x + x4.x; t1.y = x1.y + x4.y;
        float2 t2; t2.x = x2.x + x3.x; t2.y = x2.y + x3.y;
        float2 t3; t3.x = x1.x - x4.x; t3.y = x1.y - x4.y;
        float2 t4; t4.x = x2.x - x3.x; t4.y = x2.y - x3.y;
        float2 u0; u0.x = x0.x + t1.x + t2.x; u0.y = x0.y + t1.y + t2.y;
        float2 u1, u2, u3, u4;
        u1.x = x0.x + C5_1 * t1.x + C5_2 * t2.x + S5_1 * t3.y + S5_2 * t4.y;
        u1.y = x0.y + C5_1 * t1.y + C5_2 * t2.y - S5_1 * t3.x - S5_2 * t4.x;
        u2.x = x0.x + C5_2 * t1.x + C5_1 * t2.x + S5_2 * t3.y - S5_1 * t4.y;
        u2.y = x0.y + C5_2 * t1.y + C5_1 * t2.y - S5_2 * t3.x + S5_1 * t4.x;
        u3.x = x0.x + C5_2 * t1.x + C5_1 * t2.x - S5_2 * t3.y + S5_1 * t4.y;
        u3.y = x0.y + C5_2 * t1.y + C5_1 * t2.y + S5_2 * t3.x - S5_1 * t4.x;
        u4.x = x0.x + C5_1 * t1.x + C5_2 * t2.x - S5_1 * t3.y - S5_2 * t4.y;
        u4.y = x0.y + C5_1 * t1.y + C5_2 * t2.y + S5_1 * t3.x + S5_2 * t4.x;
        float sn, cs;
        __sincosf((TWO_PI_F / 320.0f) * (float)n2, &sn, &cs);
        float2 w1; w1.x = cs; w1.y = -sn;          // e^{-i 2pi n2/320}
        const float2 w2 = cmulf2(w1, w1);
        const float2 w3 = cmulf2(w2, w1);
        const float2 w4 = cmulf2(w2, w2);
        B[n2]       = u0;
        B[64 + n2]  = cmulf2(u1, w1);
        B[128 + n2] = cmulf2(u2, w2);
        B[192 + n2] = cmulf2(u3, w3);
        B[256 + n2] = cmulf2(u4, w4);
    }
    __syncthreads();
    float2* src = B;
    float2* dst = A;
#pragma unroll
    for (int s = 0; s < 5; ++s) {
        if (l < 160) {
            const int r  = l >> 5;
            const int b  = l & 31;
            const int m  = 1 << s;
            const int kk = b & (m - 1);
            const int jm = b - kk;                 // j*m
            const int j  = b >> s;
            const int base = r << 6;
            const float2 c0 = src[base + b];
            const float2 c1 = src[base + b + 32];
            float2 sm; sm.x = c0.x + c1.x; sm.y = c0.y + c1.y;
            float2 df; df.x = c0.x - c1.x; df.y = c0.y - c1.y;
            float sn, cs;
            __sincosf(PI_F * (float)j / (float)(32 >> s), &sn, &cs);
            float2 w; w.x = cs; w.y = -sn;         // e^{-i pi j / l}
            dst[base + kk + 2 * jm]     = sm;
            dst[base + kk + 2 * jm + m] = cmulf2(df, w);
        }
        __syncthreads();
        float2* t = src; src = dst; dst = t;
    }
    // 5 loop stages: B->A->B->A->B, so src==A here.  Final stage (m=32, j=0,
    // w=1): row r, position j holds Z[5j+r]; write straight to natural order.
    if (l < 160) {
        const int r = l >> 5;
        const int b = l & 31;
        const int base = r << 6;
        const float2 c0 = src[base + b];
        const float2 c1 = src[base + b + 32];
        float2 sm; sm.x = c0.x + c1.x; sm.y = c0.y + c1.y;
        float2 df; df.x = c0.x - c1.x; df.y = c0.y - c1.y;
        dst[5 * b + r]       = sm;   // Z[5*b + r]
        dst[5 * b + 160 + r] = df;   // Z[5*(b+32) + r]
    }
    __syncthreads();
    // result: B[k] = Z[k], natural order
}

// ---------------------------------------------------------------------------
// K1: STFT of 17 signals (16 = x[b][c], 1 = ref_g batch 0) via real FFT-640.
// TWO frames per block: group g = tid/160 handles frame f = 2*bx + g with
// local thread id l = tid % 160.  z[n] = wa[2n] + i*wa[2n+1] -> FFT-320 ->
// rFFT unpack (thread l=0 also handles the self-conjugate bin k=160).
// ---------------------------------------------------------------------------
__global__ __launch_bounds__(320) void k_stft(const float* __restrict__ x,
                                              const float* __restrict__ ref_g,
                                              float2* __restrict__ Sx,
                                              float2* __restrict__ refS) {
    const int s   = blockIdx.y;        // 0..16 (signal)
    const int tid = threadIdx.x;       // 0..319
    const int g   = tid / 160;         // FFT group within block
    const int l   = tid - g * 160;     // local thread id
    const int f   = 2 * blockIdx.x + g;        // frame 0..301 (301 invalid)
    const bool valid = (f < NT);

    __shared__ __align__(16) float2 A[2][320];
    __shared__ __align__(16) float2 B[2][320];
    float2* Ag = A[g];
    float2* Bg = B[g];

    const float* sig = (s < 16) ? (x + (size_t)s * TLEN) : ref_g;

#pragma unroll
    for (int h = 0; h < 2; ++h) {
        const int n = l + 160 * h;              // 0..319
        float v0 = 0.0f, v1 = 0.0f;
        if (valid) {
            const int p = f * HOP - HOP + 2 * n;    // sample index of wa[2n]
            v0 = (p >= 0 && p < TLEN) ? sig[p] : 0.0f;
            v1 = (p >= -1 && p + 1 < TLEN) ? sig[p + 1] : 0.0f;
        }
        float sn, cs;
        __sincosf((PI_F / 160.0f) * (float)n, &sn, &cs);  // angle of win[2n]
        const float w0  = 0.5f - 0.5f * cs;
        const float cs1 = cs * CD640 - sn * SD640;        // cos(theta + pi/320)
        const float w1  = 0.5f - 0.5f * cs1;
        float2 z; z.x = v0 * w0; z.y = v1 * w1;
        Ag[n] = z;
    }
    __syncthreads();

    fft320(Ag, Bg, l);

    if (valid) {
        float2* base = (s < 16) ? (Sx + (size_t)s * FT) : refS;
        for (int k = l; k <= 160; k += 160) {   // l=0 also does k=160
            const int kp = 320 - k;
            const int km = (k == 0) ? 0 : kp;   // (320-k) mod 320
            const float2 Zk = Bg[k];
            float2 Zc = Bg[km]; Zc.y = -Zc.y;   // conj(Z[(320-k) mod 320])
            const float Er = 0.5f * (Zk.x + Zc.x);
            const float Ei = 0.5f * (Zk.y + Zc.y);
            const float Dr = 0.5f * (Zk.x - Zc.x);
            const float Di = 0.5f * (Zk.y - Zc.y);
            const float Gr = Di, Gi = -Dr;      // O = -i*D
            float sp, cp;
            __sincosf((PI_F / 320.0f) * (float)k, &sp, &cp);  // phi = 2pi k/640
            float2 Xk;                          // X_k = E + e^{-i phi} O
            Xk.x = Er + cp * Gr + sp * Gi;
            Xk.y = Ei + cp * Gi - sp * Gr;
            float2 Xp;                          // X_{320-k} = conj(E) - e^{+i phi} conj(O)
            Xp.x =  Er - (cp * Di - sp * Dr);
            Xp.y = -Ei - (cp * Dr + sp * Di);
            base[(size_t)k  * NT + f] = Xk;
            base[(size_t)kp * NT + f] = Xp;     // k=0 writes Nyquist bin 320
        }
    }
}

// ---------------------------------------------------------------------------
// K2: FUSED cov-features + deep-filtering (independent work, one launch).
// Blocks [0, COV_BLOCKS): one thread per (b, kt); loads all 8 channels ONCE
//   (coalesced), emits all 74 feats rows with lane-consecutive (coalesced)
//   non-temporal stores.  Sx is read exactly once (was ~4.7x).
// Blocks [COV_BLOCKS, ...): deep filtering, unchanged math, batch 0 only;
//   rtf (146 MB, read once) loaded non-temporally.
// ---------------------------------------------------------------------------
__global__ void k_cov_df(const float2* __restrict__ Sx,
                         float* __restrict__ feats,
                         const float2* __restrict__ rtf,
                         const float2* __restrict__ refS,
                         float2* __restrict__ est) {
    if (blockIdx.x < COV_BLOCKS) {
        const int idx = blockIdx.x * 256 + threadIdx.x;
        if (idx >= COV_TOTAL) return;
        const int kt = idx % FT;
        const int b  = idx / FT;
        const float2* Sb = Sx + (size_t)b * 8 * FT;
        float* fb = feats + (size_t)b * 74 * FT + kt;
        float2 S[8];
#pragma unroll
        for (int ch = 0; ch < 8; ++ch) S[ch] = Sb[(size_t)ch * FT + kt];
        int r = 0;
#pragma unroll
        for (int i = 0; i < 8; ++i) {
#pragma unroll
            for (int j = i; j < 8; ++j) {          // upper-tri, row-major
                const float re = S[i].x * S[j].x + S[i].y * S[j].y;  // S_i*conj(S_j)
                const float im = S[i].y * S[j].x - S[i].x * S[j].y;
                __builtin_nontemporal_store(re, fb + (size_t)(r)     * FT);
                __builtin_nontemporal_store(im, fb + (size_t)(r + 1) * FT);
                r += 2;
            }
        }
        __builtin_nontemporal_store(S[3].x, fb + (size_t)72 * FT);  // REF_CH=3
        __builtin_nontemporal_store(S[3].y, fb + (size_t)73 * FT);
    } else {
        const int idx = (blockIdx.x - COV_BLOCKS) * 256 + threadIdx.x;
        if (idx >= DF_TOTAL) return;
        const int t = idx % NT;
        const int f = (idx / NT) % NF;
        const int m = idx / FT;
        float er = 0.0f, ei = 0.0f;
#pragma unroll
        for (int ki = 0; ki < 3; ++ki) {
            const int ff = f + ki - 1;
#pragma unroll
            for (int kj = 0; kj < 9; ++kj) {
                const int tt = t + kj - 4;
                float pr = 0.0f, pi = 0.0f;
                if ((unsigned)ff < (unsigned)NF && (unsigned)tt < (unsigned)NT) {
                    const float2 p = refS[(size_t)ff * NT + tt];
                    pr = p.x; pi = p.y;
                }
                const vf2 r = __builtin_nontemporal_load(
                    (const vf2*)&rtf[(size_t)(((m * 3 + ki) * 9 + kj) * NF + f) * NT + t]);
                er = fmaf(r.x, pr, er); er = fmaf(-r.y, pi, er);
                ei = fmaf(r.x, pi, ei); ei = fmaf( r.y, pr, ei);
            }
        }
        float2 o; o.x = er; o.y = ei;
        est[idx] = o;   // layout [m][f][t]
    }
}

// ---------------------------------------------------------------------------
// K4: per-frame irfft(640)*win via real-iFFT packing + complex FFT-320.
// Z_k = E_k + i O_k built from X; forward FFT of conj(Z); z[n] = conj(F[n])/320.
// The OLA 1/wsum normalization is folded in here: for output position
// t = f*320 + n - 320, wsum(t%320) = 0.5*(1 + cos^2(theta_n)) where theta_n is
// the window angle of sample n (cos(theta-pi) squares identically; ws >= 0.5
// so the reference's >1e-11 clamp never triggers).
// ---------------------------------------------------------------------------
__global__ __launch_bounds__(320) void k_iframes(const float2* __restrict__ est,
                                                 float* __restrict__ frames) {
    const int f   = blockIdx.x;  // frame
    const int m   = blockIdx.y;  // est channel
    const int tid = threadIdx.x; // 0..319

    __shared__ __align__(16) float2 Xs[322];
    __shared__ __align__(16) float2 A[320];
    __shared__ __align__(16) float2 B[320];

    {
        const float2* eb = est + (size_t)m * NF * NT + f;
        Xs[tid] = eb[(size_t)tid * NT];
        if (tid == 0) Xs[320] = eb[(size_t)320 * NT];
    }
    __syncthreads();

    if (tid <= 160) {
        const int k = tid;
        const float2 Xk = Xs[k];
        const float2 X2 = Xs[320 - k];
        const float Er = 0.5f * (Xk.x + X2.x);
        const float Ei = 0.5f * (Xk.y - X2.y);
        const float Hr = 0.5f * (Xk.x - X2.x);
        const float Hi = 0.5f * (Xk.y + X2.y);
        float sp, cp;
        __sincosf((PI_F / 320.0f) * (float)k, &sp, &cp);  // phi = 2pi k/640
        const float Or = cp * Hr - sp * Hi;               // O = e^{+i phi} H
        const float Oi = cp * Hi + sp * Hr;
        float2 vk;                   // conj(Z_k), Z_k = (Er - Oi) + i(Ei + Or)
        vk.x = Er - Oi; vk.y = -(Ei + Or);
        A[k] = vk;
        if (k >= 1 && k <= 159) {    // conj(Z_{320-k}), Z_{320-k} = (Er+Oi) + i(Or-Ei)
            float2 vp; vp.x = Er + Oi; vp.y = Ei - Or;
            A[320 - k] = vp;
        }
    }
    __syncthreads();

    fft320(A, B, tid);

    {
        const int n = tid;                       // output sample pair (2n, 2n+1)
        const float2 w = B[n];                   // F[n], natural order
        float sn, cs;
        __sincosf((PI_F / 160.0f) * (float)n, &sn, &cs);  // angle of win[2n]
        const float w0  = 0.5f - 0.5f * cs;
        const float cs1 = cs * CD640 - sn * SD640;
        const float w1  = 0.5f - 0.5f * cs1;
        const float iv0 = 1.0f / (0.5f * (1.0f + cs  * cs ));  // 1/wsum @ 2n
        const float iv1 = 1.0f / (0.5f * (1.0f + cs1 * cs1));  // 1/wsum @ 2n+1
        const float inv = 1.0f / 320.0f;
        float2 o;
        o.x = w.x * inv * w0 * iv0;
        o.y = -w.y * inv * w1 * iv1;
        float* fb = frames + ((size_t)m * NT + f) * NFFT;
        *(float2*)(fb + 2 * n) = o;
    }
}

// ---------------------------------------------------------------------------
// K5: overlap-add (frames pre-normalized) + interleaved [t][c] output write.
// ---------------------------------------------------------------------------
__global__ void k_ola(const float* __restrict__ frames,
                      const float* __restrict__ ref_g,
                      float* __restrict__ out0) {
    int idx = blockIdx.x * blockDim.x + threadIdx.x;
    if (idx >= 8 * TLEN) return;
    const int c = idx & 7;
    const int t = idx >> 3;
    float o;
    if (c == 3) {
        o = ref_g[t];
    } else {
        const int m  = (c < 3) ? c : (c - 1);
        const int f1 = t / HOP + 1;          // in [1,300]
        const int n1 = t % HOP;
        const float a = frames[((size_t)m * NT + f1)     * NFFT + n1];
        const float b = frames[((size_t)m * NT + f1 - 1) * NFFT + n1 + 320];
        o = a + b;                           // 1/wsum already folded in K4
    }
    __builtin_nontemporal_store(o, &out0[idx]);
}

extern "C" void kernel_launch(void* const* d_in, const int* in_sizes, int n_in,
                              void* d_out, int out_size, void* d_ws, size_t ws_size,
                              hipStream_t stream) {
    const float* x     = (const float*)d_in[0];   // [2,8,96000]
    const float* rtf   = (const float*)d_in[1];   // [2,7,3,9,321,301,2]
    const float* ref_g = (const float*)d_in[2];   // [2,1,96000]

    float* out0  = (float*)d_out;                 // [96000,8]
    float* feats = (float*)d_out + (size_t)8 * TLEN;  // [2,74,321,301]

    // workspace carve-up (~24 MB total)
    float2* Sx     = (float2*)d_ws;                       // 16*FT float2
    float2* refS   = Sx + (size_t)16 * FT;                // FT float2
    float2* est    = refS + (size_t)FT;                   // 7*FT float2
    float*  frames = (float*)(est + (size_t)7 * FT);      // 7*301*640 floats

    k_stft<<<dim3((NT + 1) / 2, 17), 320, 0, stream>>>(x, ref_g, Sx, refS);
    k_cov_df<<<COV_BLOCKS + DF_BLOCKS, 256, 0, stream>>>(
        Sx, feats, (const float2*)rtf, refS, est);
    k_iframes<<<dim3(NT, 7), 320, 0, stream>>>(est, frames);
    {
        const int total = 8 * TLEN;
        k_ola<<<(total + 255) / 256, 256, 0, stream>>>(frames, ref_g, out0);
    }
}